// Round 10
// baseline (335.291 us; speedup 1.0000x reference)
//
#include <hip/hip_runtime.h>
#include <hip/hip_cooperative_groups.h>

namespace cg = cooperative_groups;

#define IN_FEAT 128
#define OUT_FEAT 64
#define LRELU_ALPHA 0.2f
#define BUK_SHIFT 7        // coarse bucket = src >> 7 (128 nodes/bucket)
#define BUK_SIZE 128
#define MAX_NBUK 1024      // N <= 131072
#define D_BITS 17          // dst < 2^17: pk = (sl<<17)|dst
#define D_MASK 0x1FFFF
#define BIN_PT 8           // edges per thread in coop sort (block = 4096 edges)
#define CAP 2560           // LDS record capacity per chunk (mean bucket ~2046)
#define STAGE_MAX 5        // CAP / 512

typedef __attribute__((ext_vector_type(8))) short bf16x8;
typedef __attribute__((ext_vector_type(4))) float floatx4;

// fp32 -> bf16 bits, round-to-nearest-even (inputs are finite; no NaN guard)
__device__ __forceinline__ short f2bf(float f) {
  union { float f; unsigned u; } v; v.f = f;
  unsigned r = v.u + 0x7fff + ((v.u >> 16) & 1);
  return (short)(r >> 16);
}
__device__ __forceinline__ float bf2f(unsigned short s) {
  union { unsigned u; float f; } v; v.u = ((unsigned)s) << 16;
  return v.f;
}

// ---------------------------------------------------------------------------
// Kernel 1: h = bf16(x) @ bf16(W) via MFMA 16x16x32. Block = 4 waves = 64 rows.
// Fused: s1 = h@a1, s2 = h@a2 (quad shuffle reduction). h stored as bf16 bits.
// ---------------------------------------------------------------------------
__global__ __launch_bounds__(256) void gemm_mfma_kernel(
    const float* __restrict__ x, const float* __restrict__ W,
    const float* __restrict__ a, unsigned short* __restrict__ h,
    float* __restrict__ s1, float* __restrict__ s2, int N) {
  __shared__ __align__(16) short Wt[64 * 136];  // W^T bf16, stride 136
  __shared__ float a_sh[2 * OUT_FEAT];

  if (threadIdx.x < 2 * OUT_FEAT) a_sh[threadIdx.x] = a[threadIdx.x];
  for (int i = threadIdx.x; i < IN_FEAT * OUT_FEAT; i += 256) {
    int k = i >> 6, n = i & 63;
    Wt[n * 136 + k] = f2bf(W[i]);
  }
  __syncthreads();

  int wave = threadIdx.x >> 6;
  int lane = threadIdx.x & 63;
  int l = lane & 15;
  int quad = lane >> 4;

  int row_base = blockIdx.x * 64 + wave * 16;
  int m = row_base + l;
  int m_c = m < N ? m : N - 1;

  bf16x8 bfrag[4][4];
#pragma unroll
  for (int kt = 0; kt < 4; ++kt)
#pragma unroll
    for (int nt = 0; nt < 4; ++nt)
      bfrag[kt][nt] = *(const bf16x8*)&Wt[(nt * 16 + l) * 136 + kt * 32 + quad * 8];

  floatx4 acc[4] = {floatx4{0,0,0,0}, floatx4{0,0,0,0}, floatx4{0,0,0,0}, floatx4{0,0,0,0}};
  const float* xrow = x + (size_t)m_c * IN_FEAT;
#pragma unroll
  for (int kt = 0; kt < 4; ++kt) {
    float4 xa = *(const float4*)(xrow + kt * 32 + quad * 8);
    float4 xb = *(const float4*)(xrow + kt * 32 + quad * 8 + 4);
    bf16x8 af;
    af[0] = f2bf(xa.x); af[1] = f2bf(xa.y); af[2] = f2bf(xa.z); af[3] = f2bf(xa.w);
    af[4] = f2bf(xb.x); af[5] = f2bf(xb.y); af[6] = f2bf(xb.z); af[7] = f2bf(xb.w);
#pragma unroll
    for (int nt = 0; nt < 4; ++nt)
      acc[nt] = __builtin_amdgcn_mfma_f32_16x16x32_bf16(af, bfrag[kt][nt], acc[nt], 0, 0, 0);
  }

  int out_row = row_base + quad * 4;
#pragma unroll
  for (int reg = 0; reg < 4; ++reg) {
    int r = out_row + reg;
    if (r < N) {
#pragma unroll
      for (int nt = 0; nt < 4; ++nt)
        h[(size_t)r * OUT_FEAT + nt * 16 + l] = (unsigned short)f2bf(acc[nt][reg]);
    }
  }

  float p1[4] = {0, 0, 0, 0}, p2[4] = {0, 0, 0, 0};
#pragma unroll
  for (int nt = 0; nt < 4; ++nt) {
    float a1v = a_sh[nt * 16 + l];
    float a2v = a_sh[OUT_FEAT + nt * 16 + l];
#pragma unroll
    for (int reg = 0; reg < 4; ++reg) {
      p1[reg] += acc[nt][reg] * a1v;
      p2[reg] += acc[nt][reg] * a2v;
    }
  }
#pragma unroll
  for (int off = 1; off < 16; off <<= 1) {
#pragma unroll
    for (int reg = 0; reg < 4; ++reg) {
      p1[reg] += __shfl_xor(p1[reg], off);
      p2[reg] += __shfl_xor(p2[reg], off);
    }
  }
  if (l < 4) {
    int r = out_row + l;
    if (r < N) {
      float v1 = l == 0 ? p1[0] : (l == 1 ? p1[1] : (l == 2 ? p1[2] : p1[3]));
      float v2 = l == 0 ? p2[0] : (l == 1 ? p2[1] : (l == 2 ? p2[2] : p2[3]));
      s1[r] = v1;
      s2[r] = v2;
    }
  }
}

// ---------------------------------------------------------------------------
// Cooperative sort kernel: replaces coarse_hist + scan_buckets + bin (and the
// ee kernel) — one launch, one src/dst read. 391 blocks x 512 thr (2/CU max,
// trivially co-resident). Phases:
//   1. per-block LDS histogram of its 4096-edge slice (kept in LDS) +
//      global-atomic merge into cbuk (1024 counters, L2-hot)
//   2. grid.sync; block 0 scans cbuk -> buk_off + buk_cursor (parallel scan)
//   3. grid.sync; reserve per-(block,bucket) runs from buk_cursor using the
//      SAME LDS histogram (no re-count), scatter pk = (sl<<17)|dst from
//      registers -> ~40B contiguous runs per bucket (L2-merged)
// ---------------------------------------------------------------------------
__global__ __launch_bounds__(512) void coop_sort_kernel(
    const int* __restrict__ src, const int* __restrict__ dst,
    int* __restrict__ cbuk, int* __restrict__ buk_off,
    int* __restrict__ buk_cursor, int* __restrict__ bukdata, int E) {
  cg::grid_group grid = cg::this_grid();
  __shared__ int lhist[MAX_NBUK];
  __shared__ int lbase[MAX_NBUK];
  __shared__ int wsum[8];

  int t = threadIdx.x;
  int base_e = blockIdx.x * (512 * BIN_PT);
  int cnt_blk = min(512 * BIN_PT, E - base_e);

  for (int i = t; i < MAX_NBUK; i += 512) lhist[i] = 0;
  __syncthreads();

  // ---- Phase 1: load slice into registers + LDS histogram ----
  int s[BIN_PT], d[BIN_PT];
#pragma unroll
  for (int j = 0; j < BIN_PT; ++j) {
    int i = j * 512 + t;
    bool v = i < cnt_blk;
    int e = base_e + i;
    s[j] = v ? src[e] : 0;
    d[j] = v ? dst[e] : 0;
    if (v) atomicAdd(&lhist[s[j] >> BUK_SHIFT], 1);
  }
  __syncthreads();
  for (int i = t; i < MAX_NBUK; i += 512)
    if (lhist[i]) atomicAdd(&cbuk[i], lhist[i]);
  __threadfence();
  grid.sync();

  // ---- Phase 2: block 0 scans the 1024 bucket counts ----
  if (blockIdx.x == 0) {
    int v0 = cbuk[2 * t], v1 = cbuk[2 * t + 1];
    int ts = v0 + v1;
    int lane = t & 63, w = t >> 6;
    int xs = ts;
#pragma unroll
    for (int off = 1; off < 64; off <<= 1) {
      int y = __shfl_up(xs, off);
      if (lane >= off) xs += y;
    }
    if (lane == 63) wsum[w] = xs;
    __syncthreads();
    if (t == 0) {
      int run = 0;
#pragma unroll
      for (int i = 0; i < 8; ++i) { int u = wsum[i]; wsum[i] = run; run += u; }
    }
    __syncthreads();
    int excl = wsum[w] + (xs - ts);
    buk_off[2 * t] = excl;
    buk_off[2 * t + 1] = excl + v0;
    buk_cursor[2 * t] = excl;
    buk_cursor[2 * t + 1] = excl + v0;
    if (t == 511) buk_off[MAX_NBUK] = excl + ts;  // == E
    __threadfence();
  }
  grid.sync();

  // ---- Phase 3: reserve runs (reusing lhist counts) + scatter ----
  for (int i = t; i < MAX_NBUK; i += 512) {
    int c = lhist[i];
    lbase[i] = c > 0 ? atomicAdd(&buk_cursor[i], c) : 0;
    lhist[i] = 0;  // reuse as in-block cursor
  }
  __syncthreads();
#pragma unroll
  for (int j = 0; j < BIN_PT; ++j) {
    int i = j * 512 + t;
    if (i < cnt_blk) {
      int b = s[j] >> BUK_SHIFT;
      int pos = lbase[b] + atomicAdd(&lhist[b], 1);
      bukdata[pos] = ((s[j] & (BUK_SIZE - 1)) << D_BITS) | d[j];
    }
  }
}

// ---------------------------------------------------------------------------
// Fused sort+aggregate (EXACT round-8 structure, measured 70us): one
// 512-thread block (8 waves) per 128-node bucket (~2048 edges). Per chunk:
// stage packed edges in registers, LDS int histogram, block scan, LDS scatter
// of {dst, ee}; ee = exp(-lrelu(s1+s2)) computed once per edge in staging
// (the s2 gather + exp VALU work here overlaps the aggregate's latency —
// removing it in round 9 regressed 70->81us). Then each wave aggregates its
// 16 nodes from LDS-resident records: broadcast ds_read + coalesced 128B h
// gather (two wave-halves take alternating edges). Fused finalize.
// ---------------------------------------------------------------------------
__global__ __launch_bounds__(512) void bucket_sort_aggregate_kernel(
    const int* __restrict__ bukdata, const int* __restrict__ buk_off,
    const float* __restrict__ s1, const float* __restrict__ s2,
    const unsigned short* __restrict__ h, float* __restrict__ out, int N) {
  __shared__ float s1sh[BUK_SIZE];
  __shared__ int lhist[BUK_SIZE];
  __shared__ int loffs[BUK_SIZE];
  __shared__ int lcur[BUK_SIZE];
  __shared__ int wtot[2];
  __shared__ int2 lrec[CAP];  // 20KB

  int t = threadIdx.x;
  int buk = blockIdx.x;
  int beg = buk_off[buk];
  int end = buk_off[buk + 1];
  int node_base = buk << BUK_SHIFT;

  if (t < BUK_SIZE) {
    int ng = node_base + t;
    s1sh[t] = ng < N ? s1[ng] : 0.f;
  }

  int wid = t >> 6;      // wave 0..7; owns nodes wid, wid+8, ..., wid+120
  int lane = t & 63;
  int half = lane >> 5;
  int c2 = lane & 31;

  float ax[16], ay[16], rs[16];
#pragma unroll
  for (int j = 0; j < 16; ++j) { ax[j] = 0.f; ay[j] = 0.f; rs[j] = 0.f; }

  for (int cbeg = beg; cbeg < end; cbeg += CAP) {
    int cnt = min(end - cbeg, CAP);

    if (t < BUK_SIZE) lhist[t] = 0;
    __syncthreads();  // also covers s1sh on first chunk

    // ---- Stage: load packed edges, compute ee once/edge, LDS histogram ----
    int dreg[STAGE_MAX];
    int slreg[STAGE_MAX];
    float ereg[STAGE_MAX];
#pragma unroll
    for (int j = 0; j < STAGE_MAX; ++j) {
      int i = t + j * 512;
      bool v = i < cnt;
      int pk = v ? bukdata[cbeg + i] : 0;
      slreg[j] = pk >> D_BITS;
      dreg[j] = pk & D_MASK;
      float sc = s1sh[slreg[j]] + (v ? s2[dreg[j]] : 0.f);
      ereg[j] = __expf(-(sc > 0.f ? sc : LRELU_ALPHA * sc));
      if (v) atomicAdd(&lhist[slreg[j]], 1);
    }
    __syncthreads();

    // ---- Block scan over 128 counters (threads 0..127, 2 waves) ----
    int hv = (t < BUK_SIZE) ? lhist[t] : 0;
    int xs = hv;
#pragma unroll
    for (int off = 1; off < 64; off <<= 1) {
      int y = __shfl_up(xs, off);
      if (lane >= off) xs += y;
    }
    if (t < BUK_SIZE && lane == 63) wtot[t >> 6] = xs;
    __syncthreads();
    if (t < BUK_SIZE) {
      int base = (t >> 6) ? wtot[0] : 0;
      int excl = base + xs - hv;
      loffs[t] = excl;
      lcur[t] = excl;
    }
    __syncthreads();

    // ---- Scatter into LDS, sorted by node ----
#pragma unroll
    for (int j = 0; j < STAGE_MAX; ++j) {
      int i = t + j * 512;
      if (i < cnt) {
        int pos = atomicAdd(&lcur[slreg[j]], 1);
        lrec[pos] = make_int2(dreg[j], __float_as_int(ereg[j]));
      }
    }
    __syncthreads();

    // ---- Aggregate: wave walks its 16 nodes' LDS-contiguous records ----
#pragma unroll
    for (int nn = 0; nn < 16; ++nn) {
      int nl = wid + nn * 8;
      int o = loffs[nl];
      int c = lhist[nl];
      int k = 0;
      for (; k + 8 <= c; k += 8) {
#pragma unroll
        for (int j = 0; j < 4; ++j) {
          int2 r = lrec[o + k + 2 * j + half];  // LDS broadcast per half
          float ee = __int_as_float(r.y);
          unsigned v = *(const unsigned*)&h[r.x * OUT_FEAT + 2 * c2];
          rs[nn] += ee;
          ax[nn] += ee * bf2f(v & 0xffff);
          ay[nn] += ee * bf2f(v >> 16);
        }
      }
      for (int m = k + half; m < c; m += 2) {
        int2 r = lrec[o + m];
        float ee = __int_as_float(r.y);
        unsigned v = *(const unsigned*)&h[r.x * OUT_FEAT + 2 * c2];
        rs[nn] += ee;
        ax[nn] += ee * bf2f(v & 0xffff);
        ay[nn] += ee * bf2f(v >> 16);
      }
    }
    __syncthreads();  // protect lhist/loffs/lrec before next chunk
  }

  // ---- Finalize: cross-half reduce, out = elu(acc / rowsum) ----
#pragma unroll
  for (int nn = 0; nn < 16; ++nn) {
    float r = rs[nn] + __shfl_xor(rs[nn], 32);
    float xv = ax[nn] + __shfl_xor(ax[nn], 32);
    float yv = ay[nn] + __shfl_xor(ay[nn], 32);
    int ng = node_base + wid + nn * 8;
    if (ng < N && half == 0) {
      float vx = xv / r, vy = yv / r;
      vx = vx > 0.f ? vx : __expf(vx) - 1.f;
      vy = vy > 0.f ? vy : __expf(vy) - 1.f;
      *(float2*)&out[(size_t)ng * OUT_FEAT + 2 * c2] = make_float2(vx, vy);
    }
  }
}

extern "C" void kernel_launch(void* const* d_in, const int* in_sizes, int n_in,
                              void* d_out, int out_size, void* d_ws, size_t ws_size,
                              hipStream_t stream) {
  const float* x = (const float*)d_in[0];  // (N, 128) fp32
  const float* W = (const float*)d_in[1];  // (128, 64) fp32
  const float* a = (const float*)d_in[2];  // (1, 128) fp32
  const int* edge = (const int*)d_in[3];   // (2, E) int32

  const int N = in_sizes[0] / IN_FEAT;
  const int E = in_sizes[3] / 2;
  const int* src = edge;
  const int* dst = edge + E;

  float* out = (float*)d_out;  // (N, 64) fp32

  // Workspace layout (~21 MB)
  char* p = (char*)d_ws;
  unsigned short* h = (unsigned short*)p; p += (size_t)N * OUT_FEAT * sizeof(unsigned short);
  float* s1 = (float*)p;      p += (size_t)N * sizeof(float);
  float* s2 = (float*)p;      p += (size_t)N * sizeof(float);
  int* cbuk = (int*)p;        p += MAX_NBUK * sizeof(int);
  int* buk_off = (int*)p;     p += (MAX_NBUK + 1) * sizeof(int);
  int* buk_cursor = (int*)p;  p += MAX_NBUK * sizeof(int);
  int* bukdata = (int*)p;     p += (size_t)E * sizeof(int);

  const int NB = (N + BUK_SIZE - 1) / BUK_SIZE;  // 782 buckets

  hipMemsetAsync(cbuk, 0, MAX_NBUK * sizeof(int), stream);

  int grid_gemm = (N + 63) / 64;
  gemm_mfma_kernel<<<grid_gemm, 256, 0, stream>>>(x, W, a, h, s1, s2, N);

  int grid_sort = (E + 512 * BIN_PT - 1) / (512 * BIN_PT);  // 391 blocks
  int E_arg = E;
  void* sort_args[] = {(void*)&src, (void*)&dst, (void*)&cbuk, (void*)&buk_off,
                       (void*)&buk_cursor, (void*)&bukdata, (void*)&E_arg};
  hipLaunchCooperativeKernel((void*)coop_sort_kernel, dim3(grid_sort),
                             dim3(512), sort_args, 0, stream);

  bucket_sort_aggregate_kernel<<<NB, 512, 0, stream>>>(bukdata, buk_off, s1, s2, h, out, N);
}